// Round 2
// baseline (579.027 us; speedup 1.0000x reference)
//
#include <hip/hip_runtime.h>

typedef __bf16 bf16x8 __attribute__((ext_vector_type(8)));
typedef float  f32x4  __attribute__((ext_vector_type(4)));
typedef unsigned short u16;
typedef u16 u16x8 __attribute__((ext_vector_type(8)));

__device__ __forceinline__ u16 f2bf(float f) {
    unsigned u = __builtin_bit_cast(unsigned, f);
    return (u16)((u + 0x7FFFu + ((u >> 16) & 1u)) >> 16);  // RNE
}

// ---------------------------------------------------------------------------
// Gather + transpose + fp32->bf16, coalesced on BOTH sides via LDS tile.
// Tile: 64 k-values x 128 features per block.
//   phase 1: read feats[idx[k]][:] rows (coalesced 512B), store LDS transposed
//   phase 2: write Bt[n][k0..k0+63] as u16x8 per lane (coalesced 128B runs)
// LDS stride 66 (u16) -> <=2-way bank aliasing on both phases (free).
// ---------------------------------------------------------------------------
__global__ __launch_bounds__(256) void gather_bt(
    const float* __restrict__ feats, const int* __restrict__ idx,
    u16* __restrict__ Bt, int Kcnt, int Kpad)
{
    __shared__ u16 st[128][66];          // st[n][k_local]
    const int tid = threadIdx.x;
    const int k0  = blockIdx.x * 64;

#pragma unroll
    for (int r2 = 0; r2 < 64; r2 += 2) {
        int r = r2 + (tid >> 7);         // k_local
        int c = tid & 127;               // feature
        int k = k0 + r;
        float v = 0.f;
        if (k < Kcnt) v = feats[(size_t)idx[k] * 128 + c];
        st[c][r] = f2bf(v);
    }
    __syncthreads();

#pragma unroll
    for (int p = 0; p < 4; ++p) {
        int n  = p * 32 + (tid >> 3);
        int kk = (tid & 7) * 8;
        u16x8 v;
#pragma unroll
        for (int j = 0; j < 8; ++j) v[j] = st[n][kk + j];
        *(u16x8*)(Bt + (size_t)n * Kpad + k0 + kk) = v;
    }
}

// ---------------------------------------------------------------------------
// A-row loader: 8 consecutive f32 at koff, guarded on the final partial step.
// ---------------------------------------------------------------------------
__device__ __forceinline__ void loadA8(const float* __restrict__ ap, int koff,
                                       int K, f32x4& a0, f32x4& a1)
{
    if (koff + 8 <= K) {
        a0 = *(const f32x4*)(ap + koff);
        a1 = *(const f32x4*)(ap + koff + 4);
    } else {
#pragma unroll
        for (int j = 0; j < 4; ++j) {
            a0[j] = (koff + j     < K) ? ap[koff + j]     : 0.f;
            a1[j] = (koff + 4 + j < K) ? ap[koff + 4 + j] : 0.f;
        }
    }
}

__device__ __forceinline__ bf16x8 packA(f32x4 a0, f32x4 a1) {
    u16x8 h;
    h[0]=f2bf(a0[0]); h[1]=f2bf(a0[1]); h[2]=f2bf(a0[2]); h[3]=f2bf(a0[3]);
    h[4]=f2bf(a1[0]); h[5]=f2bf(a1[1]); h[6]=f2bf(a1[2]); h[7]=f2bf(a1[3]);
    return __builtin_bit_cast(bf16x8, h);
}

// ---------------------------------------------------------------------------
// Split-K GEMM: C[M][128] += A[M][K](f32) * B (bf16 in Bt[128][Kpad]).
// Wave = 16 rows x 128 cols (1 row-frag, 8 col-frags); block = 4 waves = 64
// rows. grid = (ceil(M/64), nsplit). A software-prefetched one k-step ahead.
// fp32 atomicAdd epilogue (C pre-zeroed); B zero-padded so A tail-garbage * 0.
// ---------------------------------------------------------------------------
__global__ __launch_bounds__(256) void gemm_bt(
    const float* __restrict__ A, const u16* __restrict__ Bt,
    float* __restrict__ C, int M, int K, int Kpad, int sps)
{
    const int wid  = threadIdx.x >> 6;
    const int lane = threadIdx.x & 63;
    const int l15  = lane & 15;
    const int lhi  = lane >> 4;

    const int row0  = blockIdx.x * 64 + wid * 16;
    const int total = (K + 31) >> 5;
    int s0 = blockIdx.y * sps;
    int s1 = s0 + sps; if (s1 > total) s1 = total;
    if (s0 >= s1) return;

    f32x4 acc[8];
#pragma unroll
    for (int j = 0; j < 8; ++j) acc[j] = (f32x4){0.f, 0.f, 0.f, 0.f};

    const int rA = min(row0 + l15, M - 1);      // clamped; garbage discarded
    const float* __restrict__ ap = A + (size_t)rA * K;
    const u16*   __restrict__ btl = Bt + (size_t)l15 * Kpad + lhi * 8;

    f32x4 ra0, ra1;                              // prefetched A (fp32)
    loadA8(ap, (s0 << 5) + lhi * 8, K, ra0, ra1);

    for (int s = s0; s < s1; ++s) {
        const int k0 = s << 5;

        f32x4 na0, na1;
        if (s + 1 < s1) loadA8(ap, ((s + 1) << 5) + lhi * 8, K, na0, na1);

        bf16x8 bfr[8];
#pragma unroll
        for (int cf = 0; cf < 8; ++cf)
            bfr[cf] = __builtin_bit_cast(bf16x8,
                *(const u16x8*)(btl + (size_t)cf * 16 * Kpad + k0));

        bf16x8 af = packA(ra0, ra1);
#pragma unroll
        for (int cf = 0; cf < 8; ++cf)
            acc[cf] = __builtin_amdgcn_mfma_f32_16x16x32_bf16(af, bfr[cf], acc[cf], 0, 0, 0);

        ra0 = na0; ra1 = na1;
    }

    // C/D layout: col = lane&15, row = (lane>>4)*4 + i
#pragma unroll
    for (int cf = 0; cf < 8; ++cf)
#pragma unroll
        for (int i = 0; i < 4; ++i) {
            int r = row0 + lhi * 4 + i;
            if (r < M)
                atomicAdd(C + (size_t)r * 128 + cf * 16 + l15, acc[cf][i]);
        }
}

// ---------------------------------------------------------------------------
// out[M][128] = relu(concat(agg[M][128], fsrc[didx[m]][128]) @ w[256][128])
// ---------------------------------------------------------------------------
__global__ __launch_bounds__(256) void dense_relu(
    const float* __restrict__ agg, const float* __restrict__ fsrc,
    const int* __restrict__ didx, const float* __restrict__ w,
    float* __restrict__ out, int M)
{
    __shared__ float sb[32][257];
    const int tid  = threadIdx.x;
    const int row0 = blockIdx.x * 32;

    for (int i = tid; i < 32 * 32; i += 256) {           // agg half
        int r = i >> 5, c4 = (i & 31) << 2;
        int gr = row0 + r;
        f32x4 v = (f32x4){0.f, 0.f, 0.f, 0.f};
        if (gr < M) v = *(const f32x4*)(agg + (size_t)gr * 128 + c4);
        sb[r][c4 + 0] = v[0]; sb[r][c4 + 1] = v[1];
        sb[r][c4 + 2] = v[2]; sb[r][c4 + 3] = v[3];
    }
    for (int i = tid; i < 32 * 32; i += 256) {           // gathered dst half
        int r = i >> 5, c4 = (i & 31) << 2;
        int gr = row0 + r;
        int sr = (gr < M) ? didx[gr] : 0;
        f32x4 v = *(const f32x4*)(fsrc + (size_t)sr * 128 + c4);
        sb[r][128 + c4 + 0] = v[0]; sb[r][128 + c4 + 1] = v[1];
        sb[r][128 + c4 + 2] = v[2]; sb[r][128 + c4 + 3] = v[3];
    }
    __syncthreads();

    const int colg = (tid & 15) << 3;   // 8-col slab
    const int r0l  = (tid >> 4) * 2;    // 2 rows
    float acc0[8], acc1[8];
#pragma unroll
    for (int c = 0; c < 8; ++c) { acc0[c] = 0.f; acc1[c] = 0.f; }

    for (int j = 0; j < 256; ++j) {
        f32x4 wa = *(const f32x4*)(w + j * 128 + colg);
        f32x4 wb = *(const f32x4*)(w + j * 128 + colg + 4);
        float a0 = sb[r0l][j];
        float a1 = sb[r0l + 1][j];
#pragma unroll
        for (int c = 0; c < 4; ++c) {
            acc0[c]     += a0 * wa[c];  acc0[c + 4] += a0 * wb[c];
            acc1[c]     += a1 * wa[c];  acc1[c + 4] += a1 * wb[c];
        }
    }

    int gr0 = row0 + r0l;
    if (gr0 < M) {
#pragma unroll
        for (int c = 0; c < 8; ++c)
            out[(size_t)gr0 * 128 + colg + c] = fmaxf(acc0[c], 0.f);
    }
    int gr1 = gr0 + 1;
    if (gr1 < M) {
#pragma unroll
        for (int c = 0; c < 8; ++c)
            out[(size_t)gr1 * 128 + colg + c] = fmaxf(acc1[c], 0.f);
    }
}

// ---------------------------------------------------------------------------
extern "C" void kernel_launch(void* const* d_in, const int* in_sizes, int n_in,
                              void* d_out, int out_size, void* d_ws, size_t ws_size,
                              hipStream_t stream)
{
    const float* src_nodes = (const float*)d_in[0];
    const int*   s1idx     = (const int*)d_in[1];
    const int*   s2idx     = (const int*)d_in[2];
    const int*   d1idx     = (const int*)d_in[3];
    const int*   d2idx     = (const int*)d_in[4];
    const float* dif1      = (const float*)d_in[5];
    const float* dif2      = (const float*)d_in[6];
    const float* w1        = (const float*)d_in[7];
    const float* w2        = (const float*)d_in[8];
    float*       out       = (float*)d_out;

    const int S2 = 16000, M2 = 4000, S1 = 3500, M1 = 1024;
    const int K2 = 16000, K1 = 3500;
    const int Kpad2 = 16000;                 // multiple of 64
    const int Kpad1 = 3520;                  // 3500 padded to 64-multiple

    char* ws = (char*)d_ws;
    size_t off = 0;
    float* agg2 = (float*)(ws + off); off += (size_t)M2 * 128 * 4;
    float* agg1 = (float*)(ws + off); off += (size_t)M1 * 128 * 4;
    float* x    = (float*)(ws + off); off += (size_t)M2 * 128 * 4;
    u16*   Bt2  = (u16*)(ws + off);   off += (size_t)128 * Kpad2 * 2;
    u16*   Bt1  = (u16*)(ws + off);   off += (size_t)128 * Kpad1 * 2;

    // zero both atomic accumulators (contiguous)
    hipMemsetAsync(agg2, 0, (size_t)(M2 + M1) * 128 * 4, stream);

    // ---- hop 2 ----
    gather_bt<<<Kpad2 / 64, 256, 0, stream>>>(src_nodes, s2idx, Bt2, S2, Kpad2);

    {
        // total k-steps = 500; sps=50 -> 10 splits; grid 63x10 = 630 blocks
        dim3 grid((M2 + 63) / 64, 10);
        gemm_bt<<<grid, 256, 0, stream>>>(dif2, Bt2, agg2, M2, K2, Kpad2, 50);
    }

    dense_relu<<<(M2 + 31) / 32, 256, 0, stream>>>(agg2, src_nodes, d2idx, w1, x, M2);

    // ---- hop 1 ----
    gather_bt<<<Kpad1 / 64, 256, 0, stream>>>(x, s1idx, Bt1, S1, Kpad1);

    {
        // total k-steps = 110; sps=5 -> 22 splits; grid 16x22 = 352 blocks
        dim3 grid((M1 + 63) / 64, 22);
        gemm_bt<<<grid, 256, 0, stream>>>(dif1, Bt1, agg1, M1, K1, Kpad1, 5);
    }

    dense_relu<<<(M1 + 31) / 32, 256, 0, stream>>>(agg1, x, d1idx, w2, out, M1);
}